// Round 12
// baseline (3674.208 us; speedup 1.0000x reference)
//
#include <hip/hip_runtime.h>
#include <stdint.h>

#define T_MAX 512
#define BATCH 64
#define NCLS  128
#define BEAM  32
#define TBL   6144
#define NEGF  (-1e30f)
#define EMPTYK ((int)0x80000000)
#define HPRIME 1000003u
#define SCAP  256

// jnp.logaddexp: max + log1p(exp(-|a-b|)) (all values finite here)
__device__ __forceinline__ float lae(float a, float b) {
  float mx = fmaxf(a, b);
  return mx + log1pf(expf(-fabsf(a - b)));
}
// monotonic float <-> uint mapping for ordering / atomicMax on floats
__device__ __forceinline__ unsigned encf(float x) {
  unsigned v = __float_as_uint(x);
  return (v & 0x80000000u) ? ~v : (v | 0x80000000u);
}
__device__ __forceinline__ float decf(unsigned u) {
  unsigned v = (u & 0x80000000u) ? (u ^ 0x80000000u) : ~u;
  return __uint_as_float(v);
}
__device__ __forceinline__ unsigned lowkey(unsigned h) {
  return 0xFFFFFFFFu - (h ^ 0x80000000u);   // smaller signed hash ranks higher
}

__device__ __forceinline__ int tbl_insert(int* key, int h) {
  unsigned x = (unsigned)h * 2654435761u;
  x ^= x >> 16;
  int j = (int)(((unsigned long long)x * (unsigned long long)TBL) >> 32);
  for (;;) {
    int cur = key[j];
    if (cur == EMPTYK) cur = atomicCAS(&key[j], EMPTYK, h);
    if (cur == EMPTYK || cur == h) return j;
    ++j; if (j == TBL) j = 0;
  }
}

__device__ __forceinline__ unsigned long long shflx64(unsigned long long v, int m) {
  unsigned lo = (unsigned)__shfl_xor((int)(unsigned)v, m, 64);
  unsigned hi = (unsigned)__shfl_xor((int)(unsigned)(v >> 32), m, 64);
  return ((unsigned long long)hi << 32) | lo;
}

// Descending bitonic sort of 64 x u32 across one wave (R3-verified network, R=1)
__device__ __forceinline__ unsigned bitonic64_u32_desc(int ln, unsigned v) {
  #pragma unroll
  for (int size = 2; size <= 64; size <<= 1) {
    #pragma unroll
    for (int stride = size >> 1; stride > 0; stride >>= 1) {
      const unsigned o = (unsigned)__shfl_xor((int)v, stride, 64);
      const bool keepMax = (((ln & size) == 0) == ((ln & stride) == 0));
      v = keepMax ? (v > o ? v : o) : (v < o ? v : o);
    }
  }
  return v;
}

__global__ __launch_bounds__(512, 1)
void ctc_beam_kernel(const float* __restrict__ data,
                     const int* __restrict__ dlen,
                     int* __restrict__ out) {
  // rare-path hash table — touched only on anomalies / overflow
  __shared__ int       tkey[TBL];
  __shared__ unsigned  tmax[TBL];
  __shared__ unsigned  tsum[TBL];
  __shared__ unsigned  tmin[TBL];
  __shared__ unsigned short bp[T_MAX * BEAM];  // backptr: parent|cls<<5|ext<<12
  __shared__ __align__(16) float lpbuf[2][NCLS];
  __shared__ int   bhash[2][BEAM];
  __shared__ float bpb[2][BEAM], bpnb[2][BEAM];
  __shared__ int   blen[2][BEAM], blast[2][BEAM];
  __shared__ float sptot[BEAM], s_pb[BEAM], s_pnb[BEAM], s_pnbm[BEAM];
  __shared__ int   stay_slot[BEAM];
  __shared__ unsigned thsub[64];          // [0..31]=stay keys, [32..63]=parentBest
  __shared__ int anom, ovf;
  __shared__ int scnt[2];                 // parity-buffered survivor count
  __shared__ unsigned long long skey[SCAP + 16];  // +16 pad for batched reads
  __shared__ unsigned sidx[SCAP];
  // rare-path selection scratch
  __shared__ unsigned long long wkey[8 * BEAM];
  __shared__ unsigned widx[8 * BEAM];
  __shared__ unsigned sel[BEAM];
  __shared__ int seqbuf[T_MAX];
  __shared__ int flen_s;

  const int tid = threadIdx.x;
  const int b = blockIdx.x;
  int L = dlen[b];
  L = L < 0 ? 0 : (L > T_MAX ? T_MAX : L);

  if (tid < BEAM) {
    bhash[0][tid] = tid;
    bpb[0][tid]   = (tid == 0) ? 0.0f : NEGF;
    bpnb[0][tid]  = NEGF;
    blen[0][tid]  = 0;
    blast[0][tid] = -1;
  }
  if (tid == 0) { anom = 0; ovf = 0; scnt[0] = 0; scnt[1] = 0; }
  if (tid < NCLS && L > 0) lpbuf[0][tid] = data[(size_t)b * NCLS + tid];
  __syncthreads();

  int cb = 0;
  for (int t = 0; t < L; ++t) {
    const int par = t & 1;
    const bool haspre = (tid >= 256) && (tid < 256 + NCLS) && (t + 1 < L);
    float pre = 0.0f;
    if (haspre) pre = data[((size_t)(t + 1) * BATCH + b) * NCLS + (tid - 256)];
    float* lpc = lpbuf[par];

    // ======== phase K': fused merge-scan + extend keys + stays ========
    const int i  = tid >> 4;
    const int c0 = (tid & 15) << 3;
    const unsigned hb = (unsigned)bhash[cb][i] * HPRIME;
    const float pbi = bpb[cb][i];
    const float pti = lae(pbi, bpnb[cb][i]);
    const int   lsti = blast[cb][i];
    const unsigned myh = (unsigned)bhash[cb][tid & 31];

    unsigned mmask = 0;
    int anomr = 0, cnt = 0;
    float e1 = NEGF;
    #pragma unroll
    for (int q = 0; q < 32; ++q) {
      const unsigned hq = (unsigned)bhash[cb][q];       // broadcast read
      const unsigned rel = hq - hb - 1u - (unsigned)c0;
      if (rel < 8u) mmask |= 1u << rel;                 // extend swallowed by stay
      if (tid < 32) {
        const unsigned cs = myh - hq * HPRIME - 1u;     // extend(q,cs) -> my stay
        if (cs < (unsigned)NCLS) {
          if (cnt == 0) {
            const float pbq = bpb[cb][q], pnbq = bpnb[cb][q];
            const float ptq = lae(pbq, pnbq);
            const int lsq = blast[cb][q];
            e1 = (cs == 0u) ? NEGF
               : ((((int)cs == lsq) ? pbq : ptq) + lpc[cs]);
          }
          ++cnt;
        }
        if (q != tid) {                                 // extend-extend collision?
          const unsigned d = (myh - hq) * HPRIME;
          if (d + 127u <= 254u) anomr = 1;
        }
      }
    }

    unsigned long long k8[8];
    {
      const float4 l0 = ((const float4*)(lpc + c0))[0];
      const float4 l1 = ((const float4*)(lpc + c0))[1];
      const float lv[8] = {l0.x, l0.y, l0.z, l0.w, l1.x, l1.y, l1.z, l1.w};
      unsigned pbest = 0u;
      #pragma unroll
      for (int k = 0; k < 8; ++k) {
        const int c = c0 + k;
        const float x = (c == 0) ? NEGF : (((c == lsti) ? pbi : pti) + lv[k]);
        const float tot = fmaxf(x, NEGF);   // == lae(NEGF,x) bitwise
        const unsigned h = hb + (unsigned)(c + 1);
        unsigned long long key =
            ((unsigned long long)encf(tot) << 32) |
            (unsigned long long)lowkey(h);
        if (((mmask >> k) & 1u) || c == 0) key = 0ull;  // merged or blank
        k8[k] = key;
        const unsigned e32 = (unsigned)(key >> 32);
        pbest = pbest > e32 ? pbest : e32;
      }
      // 16-lane shuffle max -> parentBest (no atomics, no pre-clear)
      #pragma unroll
      for (int m = 1; m <= 8; m <<= 1) {
        const unsigned o = (unsigned)__shfl_xor((int)pbest, m, 64);
        pbest = pbest > o ? pbest : o;
      }
      if ((tid & 15) == 0) thsub[32 + i] = pbest;
    }
    if (tid < BEAM) {
      const int j = tid;
      if (cnt > 1) anomr = 1;
      const float pbv = bpb[cb][j], pnbv = bpnb[cb][j];
      const float pt = lae(pbv, pnbv);
      sptot[j] = pt;
      const float spb = pt + lpc[0];
      s_pb[j] = spb;
      const int lstj = blast[cb][j];
      const float spnb = pnbv + ((lstj >= 0) ? lpc[lstj] : NEGF);
      s_pnb[j] = spnb;
      float pnbm;
      if (cnt == 1) {
        const float m = fmaxf(spnb, e1);
        const float s = expf(spnb - m) + expf(e1 - m);  // stay term first (ref order)
        pnbm = m + logf(s);
      } else {
        pnbm = spnb;
      }
      s_pnbm[j] = pnbm;
      thsub[j] = encf(lae(spb, pnbm));
      if (anomr) anom = 1;
    }
    if (tid == 511) scnt[par ^ 1] = 0;   // reset next step's survivor counter
    __syncthreads();  // B

    const bool an = (anom != 0);
    bool dorare = an;
    if (!an) {
      // ======== phase F: wave-redundant u32 bitonic theta + filter/compact ====
      const int ln = tid & 63;
      const unsigned sorted = bitonic64_u32_desc(ln, thsub[ln]);
      const unsigned thr = (unsigned)__shfl((int)sorted, 31, 64);  // 32nd largest

      int myn = 0;
      #pragma unroll
      for (int k = 0; k < 8; ++k) myn += ((unsigned)(k8[k] >> 32) >= thr) ? 1 : 0;
      const bool stayS = (tid < BEAM) && (thsub[tid] >= thr);
      myn += stayS ? 1 : 0;
      if (myn) {
        int o = atomicAdd(&scnt[par], myn);
        if (o + myn <= SCAP) {
          #pragma unroll
          for (int k = 0; k < 8; ++k) {
            if ((unsigned)(k8[k] >> 32) >= thr) {
              skey[o] = k8[k];
              sidx[o] = (unsigned)(BEAM + i * NCLS + (c0 + k));
              ++o;
            }
          }
          if (stayS) {
            skey[o] = ((unsigned long long)thsub[tid] << 32) |
                      (unsigned long long)lowkey((unsigned)bhash[cb][tid]);
            sidx[o] = (unsigned)tid;
          }
        } else ovf = 1;
      }
      __syncthreads();  // D
      dorare = (ovf != 0);
    }

    if (!dorare) {
      // ======== phase R: rank-by-count + update; idle threads do housekeeping ==
      const int scr = scnt[par];
      if (tid < scr) {                           // scr <= 256: rankers are tid<256
        const unsigned long long kq = skey[tid];
        int rank = 0;
        for (int p0 = 0; p0 < scr; p0 += 16) {
          #pragma unroll
          for (int pp = 0; pp < 16; ++pp) {
            const unsigned long long kp = skey[p0 + pp];   // padded, in-bounds
            rank += ((p0 + pp) < scr && kp > kq) ? 1 : 0;
          }
        }
        if (rank < BEAM) {
          const int j = rank;
          const unsigned s = sidx[tid];
          int nh, p, cls, ex; float npb, npnb;
          if (s < BEAM) {                     // stay-rooted segment
            p = (int)s; cls = 0; ex = 0;
            nh = bhash[cb][p];
            npb = s_pb[p];
            npnb = s_pnbm[p];
          } else {                            // standalone extend
            const unsigned q = s - BEAM;
            p = (int)(q >> 7); cls = (int)(q & 127); ex = 1;
            nh = (int)((unsigned)bhash[cb][p] * HPRIME + (unsigned)(cls + 1));
            npb = NEGF;
            npnb = (cls == 0) ? NEGF
                 : (((cls == blast[cb][p]) ? bpb[cb][p] : sptot[p]) + lpc[cls]);
          }
          const int plen = blen[cb][p], plast = blast[cb][p];
          const int nb = cb ^ 1;
          bhash[nb][j] = nh; bpb[nb][j] = npb; bpnb[nb][j] = npnb;
          blen[nb][j]  = plen + ex;
          blast[nb][j] = ex ? cls : plast;
          bp[t * BEAM + j] = (unsigned short)(p | (cls << 5) | (ex << 12));
        }
      }
      if (haspre) lpbuf[par ^ 1][tid - 256] = pre;
      __syncthreads();  // E
    } else {
      // ================= RARE PATH: full hash table (proven R1 semantics) =====
      for (int m = tid; m < TBL; m += 512) {
        tkey[m] = EMPTYK; tmax[m] = 0u; tsum[m] = 0u; tmin[m] = 0xFFFFFFFFu;
      }
      __syncthreads();

      int eslot[8]; float ex_[8];
      {
        #pragma unroll
        for (int k = 0; k < 8; ++k) {
          const int c = c0 + k;
          int h = (int)(hb + (unsigned)(c + 1));
          if (h == EMPTYK) h = (int)0x80000001u;
          const float x = (c == 0) ? NEGF : (((c == lsti) ? pbi : pti) + lpc[c]);
          const int s = tbl_insert(tkey, h);
          atomicMax(&tmax[s], encf(x));
          atomicMin(&tmin[s], (unsigned)(BEAM + i * NCLS + c));
          eslot[k] = s; ex_[k] = x;
        }
      }
      if (tid < BEAM) {
        const int s = tbl_insert(tkey, bhash[cb][tid]);
        atomicMax(&tmax[s], encf(s_pnb[tid]));
        atomicMin(&tmin[s], (unsigned)tid);
        stay_slot[tid] = s;
      }
      __syncthreads();

      #pragma unroll
      for (int k = 0; k < 8; ++k) {
        const int s = eslot[k];
        atomicAdd((float*)&tsum[s], expf(ex_[k] - decf(tmax[s])));
      }
      if (tid < BEAM) {
        const int s = stay_slot[tid];
        atomicAdd((float*)&tsum[s], expf(s_pnb[tid] - decf(tmax[s])));
      }
      __syncthreads();

      for (int m = tid; m < TBL; m += 512) {
        if (tkey[m] != EMPTYK) {
          const float mm = decf(tmax[m]);
          const float ss = __uint_as_float(tsum[m]);
          const float pnbm = mm + logf(ss);
          tmax[m] = __float_as_uint(pnbm);
          tsum[m] = encf(lae(NEGF, pnbm));
        }
      }
      __syncthreads();
      if (tid < BEAM) {
        const int s = stay_slot[tid];
        tsum[s] = encf(lae(s_pb[tid], __uint_as_float(tmax[s])));
      }
      __syncthreads();

      {
        const int wv = tid >> 6, ln = tid & 63;
        const int base = wv * (TBL / 8) + ln * (TBL / 512);
        unsigned long long kk2[TBL / 512];
        #pragma unroll
        for (int m = 0; m < TBL / 512; ++m) {
          const int idx = base + m;
          if (tkey[idx] != EMPTYK) {
            kk2[m] = ((unsigned long long)tsum[idx] << 32) |
                     (unsigned long long)lowkey((unsigned)tkey[idx]);
          } else kk2[m] = 0ull;
        }
        unsigned cons = 0;
        for (int it = 0; it < BEAM; ++it) {
          unsigned long long best = 0ull; int bi = -1;
          #pragma unroll
          for (int m = 0; m < TBL / 512; ++m)
            if (!((cons >> m) & 1u) && kk2[m] > best) { best = kk2[m]; bi = m; }
          unsigned long long wm = best;
          #pragma unroll
          for (int off = 32; off > 0; off >>= 1) {
            const unsigned long long o = shflx64(wm, off);
            if (o > wm) wm = o;
          }
          const unsigned long long ball = __ballot(best == wm && wm != 0ull);
          const int winner = ball ? (__ffsll((long long)ball) - 1) : -1;
          if (ln == winner) {
            cons |= 1u << bi;
            wkey[wv * BEAM + it] = wm;
            widx[wv * BEAM + it] = (unsigned)(base + bi);
          } else if (winner < 0 && ln == 0) {
            wkey[wv * BEAM + it] = 0ull;
            widx[wv * BEAM + it] = 0xFFFFFFFFu;
          }
        }
      }
      __syncthreads();
      if (tid < 64) {
        unsigned long long kk2[4]; unsigned ii[4];
        #pragma unroll
        for (int m = 0; m < 4; ++m) { kk2[m] = wkey[tid * 4 + m]; ii[m] = widx[tid * 4 + m]; }
        unsigned cons = 0;
        for (int it = 0; it < BEAM; ++it) {
          unsigned long long best = 0ull; int bi = -1;
          #pragma unroll
          for (int m = 0; m < 4; ++m)
            if (!((cons >> m) & 1u) && kk2[m] > best) { best = kk2[m]; bi = m; }
          unsigned long long wm = best;
          #pragma unroll
          for (int off = 32; off > 0; off >>= 1) {
            const unsigned long long o = shflx64(wm, off);
            if (o > wm) wm = o;
          }
          const unsigned long long ball = __ballot(best == wm && wm != 0ull);
          const int winner = ball ? (__ffsll((long long)ball) - 1) : -1;
          if (tid == winner) { cons |= 1u << bi; sel[it] = ii[bi]; }
          else if (winner < 0 && tid == 0) sel[it] = 0xFFFFFFFFu;
        }
      }
      __syncthreads();

      if (tid < BEAM) {
        const int j = tid;
        const unsigned s = sel[j];
        int nh, p, cls, ex; float npb, npnb;
        if (s != 0xFFFFFFFFu) {
          nh = tkey[s];
          npnb = __uint_as_float(tmax[s]);
          npb = NEGF;
          #pragma unroll
          for (int q = 0; q < BEAM; ++q)
            if (stay_slot[q] == (int)s) npb = s_pb[q];
          const unsigned mi = tmin[s];
          ex  = (mi >= BEAM) ? 1 : 0;
          p   = ex ? (int)((mi - BEAM) >> 7) : (int)mi;
          cls = ex ? (int)((mi - BEAM) & 127) : 0;
          p &= 31;
        } else {
          nh = 0x7F000000 + j; npb = NEGF; npnb = NEGF; p = j; cls = 0; ex = 0;
        }
        const int plen = blen[cb][p], plast = blast[cb][p];
        const int nb = cb ^ 1;
        bhash[nb][j] = nh; bpb[nb][j] = npb; bpnb[nb][j] = npnb;
        blen[nb][j]  = plen + ex;
        blast[nb][j] = ex ? cls : plast;
        bp[t * BEAM + j] = (unsigned short)(p | (cls << 5) | (ex << 12));
      }
      if (tid == 511) { anom = 0; ovf = 0; }
      if (haspre) lpbuf[par ^ 1][tid - 256] = pre;
      __syncthreads();
    }
    cb ^= 1;
  }

  // ---- final top-1 + path reconstruction via backpointers
  if (tid == 0) {
    float bt = -3.4e38f; int bj = 0;
    for (int j = 0; j < BEAM; ++j) {
      const float tt = lae(bpb[cb][j], bpnb[cb][j]);
      if (tt > bt) { bt = tt; bj = j; }   // strict > : lowest index wins ties
    }
    int cur = bj;
    int pos = blen[cb][bj];
    flen_s = pos;
    for (int tt = L - 1; tt >= 0; --tt) {
      const unsigned short e = bp[tt * BEAM + cur];
      const int p = e & 31, cl = (e >> 5) & 127, ex = (e >> 12) & 1;
      if (ex) { --pos; if (pos >= 0) seqbuf[pos] = cl; }
      cur = p;
    }
  }
  __syncthreads();
  const int fl = flen_s;
  for (int k = tid; k < T_MAX; k += 512) {
    out[(size_t)b * T_MAX + k] = (k < fl) ? seqbuf[k] : 0;
  }
}

extern "C" void kernel_launch(void* const* d_in, const int* in_sizes, int n_in,
                              void* d_out, int out_size, void* d_ws, size_t ws_size,
                              hipStream_t stream) {
  const float* data = (const float*)d_in[0];   // [512, 64, 128] f32 log-probs
  const int*   dlen = (const int*)d_in[1];     // [64] int32
  int* out = (int*)d_out;                      // [64, 512] int32
  (void)in_sizes; (void)n_in; (void)out_size; (void)d_ws; (void)ws_size;
  hipLaunchKernelGGL(ctc_beam_kernel, dim3(BATCH), dim3(512), 0, stream,
                     data, dlen, out);
}

// Round 13
// 2261.204 us; speedup vs baseline: 1.6249x; 1.6249x over previous
//
#include <hip/hip_runtime.h>
#include <stdint.h>

#define T_MAX 512
#define BATCH 64
#define NCLS  128
#define BEAM  32
#define TBL   6144
#define NEGF  (-1e30f)
#define EMPTYK ((int)0x80000000)
#define HPRIME 1000003u
#define SCAP  256

// jnp.logaddexp: max + log1p(exp(-|a-b|)) (all values finite here)
__device__ __forceinline__ float lae(float a, float b) {
  float mx = fmaxf(a, b);
  return mx + log1pf(expf(-fabsf(a - b)));
}
// monotonic float <-> uint mapping for ordering / atomicMax on floats
__device__ __forceinline__ unsigned encf(float x) {
  unsigned v = __float_as_uint(x);
  return (v & 0x80000000u) ? ~v : (v | 0x80000000u);
}
__device__ __forceinline__ float decf(unsigned u) {
  unsigned v = (u & 0x80000000u) ? (u ^ 0x80000000u) : ~u;
  return __uint_as_float(v);
}
__device__ __forceinline__ unsigned lowkey(unsigned h) {
  return 0xFFFFFFFFu - (h ^ 0x80000000u);   // smaller signed hash ranks higher
}

__device__ __forceinline__ int tbl_insert(int* key, int h) {
  unsigned x = (unsigned)h * 2654435761u;
  x ^= x >> 16;
  int j = (int)(((unsigned long long)x * (unsigned long long)TBL) >> 32);
  for (;;) {
    int cur = key[j];
    if (cur == EMPTYK) cur = atomicCAS(&key[j], EMPTYK, h);
    if (cur == EMPTYK || cur == h) return j;
    ++j; if (j == TBL) j = 0;
  }
}

__device__ __forceinline__ unsigned long long shflx64(unsigned long long v, int m) {
  unsigned lo = (unsigned)__shfl_xor((int)(unsigned)v, m, 64);
  unsigned hi = (unsigned)__shfl_xor((int)(unsigned)(v >> 32), m, 64);
  return ((unsigned long long)hi << 32) | lo;
}

// Descending bitonic sort of 64 x u32 across one wave (R3-verified network, R=1)
__device__ __forceinline__ unsigned bitonic64_u32_desc(int ln, unsigned v) {
  #pragma unroll
  for (int size = 2; size <= 64; size <<= 1) {
    #pragma unroll
    for (int stride = size >> 1; stride > 0; stride >>= 1) {
      const unsigned o = (unsigned)__shfl_xor((int)v, stride, 64);
      const bool keepMax = (((ln & size) == 0) == ((ln & stride) == 0));
      v = keepMax ? (v > o ? v : o) : (v < o ? v : o);
    }
  }
  return v;
}

__global__ __launch_bounds__(512, 1)
void ctc_beam_kernel(const float* __restrict__ data,
                     const int* __restrict__ dlen,
                     int* __restrict__ out) {
  // rare-path hash table — touched only on anomalies / overflow
  __shared__ int       tkey[TBL];
  __shared__ unsigned  tmax[TBL];
  __shared__ unsigned  tsum[TBL];
  __shared__ unsigned  tmin[TBL];
  __shared__ unsigned short bp[T_MAX * BEAM];  // backptr: parent|cls<<5|ext<<12
  __shared__ __align__(16) float lpbuf[2][NCLS];
  __shared__ int   bhash[2][BEAM];
  __shared__ float bpb[2][BEAM], bpnb[2][BEAM];
  __shared__ int   blen[2][BEAM], blast[2][BEAM];
  __shared__ float sptot[BEAM], s_pb[BEAM], s_pnb[BEAM], s_pnbm[BEAM];
  __shared__ int   stay_slot[BEAM];
  __shared__ unsigned char mergeTo[BEAM * NCLS];  // 0xFF = not merged
  __shared__ int mergeCnt[BEAM], mergeFrom[BEAM];
  __shared__ unsigned thsub[64];          // [0..31]=stay keys, [32..63]=parentBest
  __shared__ int anom, ovf;
  __shared__ int scnt[2];                 // parity-buffered survivor count
  __shared__ unsigned long long skey[SCAP + 16];  // +16 pad for batched reads
  __shared__ unsigned sidx[SCAP];
  // rare-path selection scratch
  __shared__ unsigned long long wkey[8 * BEAM];
  __shared__ unsigned widx[8 * BEAM];
  __shared__ unsigned sel[BEAM];
  __shared__ int seqbuf[T_MAX];
  __shared__ int flen_s;

  const int tid = threadIdx.x;
  const int b = blockIdx.x;
  int L = dlen[b];
  L = L < 0 ? 0 : (L > T_MAX ? T_MAX : L);

  if (tid < BEAM) {
    bhash[0][tid] = tid;
    bpb[0][tid]   = (tid == 0) ? 0.0f : NEGF;
    bpnb[0][tid]  = NEGF;
    blen[0][tid]  = 0;
    blast[0][tid] = -1;
    mergeCnt[tid] = 0;
  }
  {
    unsigned* mtw = (unsigned*)mergeTo;
    for (int m = tid; m < (BEAM * NCLS) / 4; m += 512) mtw[m] = 0xFFFFFFFFu;
  }
  if (tid == 0) { anom = 0; ovf = 0; scnt[0] = 0; scnt[1] = 0; }
  if (tid < NCLS && L > 0) lpbuf[0][tid] = data[(size_t)b * NCLS + tid];
  __syncthreads();

  int cb = 0;
  for (int t = 0; t < L; ++t) {
    const int par = t & 1;
    const bool haspre = (tid >= 256) && (tid < 256 + NCLS) && (t + 1 < L);
    float pre = 0.0f;
    if (haspre) pre = data[((size_t)(t + 1) * BATCH + b) * NCLS + (tid - 256)];
    float* lpc = lpbuf[par];

    // ======== phase D: stays + exact merge detection ========
    if (tid < BEAM) {
      const float pbv = bpb[cb][tid], pnbv = bpnb[cb][tid];
      const float pt = lae(pbv, pnbv);
      sptot[tid] = pt;
      s_pb[tid]  = pt + lpc[0];
      const int lsti = blast[cb][tid];
      s_pnb[tid] = pnbv + ((lsti >= 0) ? lpc[lsti] : NEGF);
    }
    for (int k = tid; k < BEAM * BEAM; k += 512) {
      const int j = k >> 5, i2 = k & 31;
      const unsigned hj = (unsigned)bhash[cb][j];
      const unsigned hip = (unsigned)bhash[cb][i2] * HPRIME;
      const unsigned c = hj - hip - 1u;
      if (c < (unsigned)NCLS) {                 // extend(i2,c) merges stay j
        atomicAdd(&mergeCnt[j], 1);
        mergeFrom[j] = (i2 << 8) | (int)c;
        mergeTo[i2 * NCLS + (int)c] = (unsigned char)j;
      }
      if (j < i2) {                              // extend-extend collision?
        const unsigned d = (hj - (unsigned)bhash[cb][i2]) * HPRIME;
        if (d + 127u <= 254u) anom = 1;
      }
    }
    __syncthreads();  // A

    // ======== phase K: extend keys + per-parent best + stay keys ========
    const int i  = tid >> 4;
    const int c0 = (tid & 15) << 3;
    unsigned long long k8[8];
    {
      const float pbi = bpb[cb][i];
      const float pti = sptot[i];
      const int   lsti = blast[cb][i];
      const unsigned hb = (unsigned)bhash[cb][i] * HPRIME;
      const float4 l0 = ((const float4*)(lpc + c0))[0];
      const float4 l1 = ((const float4*)(lpc + c0))[1];
      const float lv[8] = {l0.x, l0.y, l0.z, l0.w, l1.x, l1.y, l1.z, l1.w};
      const unsigned m0 = ((const unsigned*)&mergeTo[i * NCLS + c0])[0];
      const unsigned m1 = ((const unsigned*)&mergeTo[i * NCLS + c0])[1];
      unsigned pbest = 0u;
      #pragma unroll
      for (int k = 0; k < 8; ++k) {
        const int c = c0 + k;
        const unsigned mb = ((k < 4 ? (m0 >> (8 * k)) : (m1 >> (8 * (k - 4)))) & 0xFFu);
        const float x = (c == 0) ? NEGF : (((c == lsti) ? pbi : pti) + lv[k]);
        const float tot = fmaxf(x, NEGF);   // == lae(NEGF,x) bitwise
        const unsigned h = hb + (unsigned)(c + 1);
        unsigned long long key =
            ((unsigned long long)encf(tot) << 32) |
            (unsigned long long)lowkey(h);
        if (mb != 0xFFu || c == 0) key = 0ull;   // merged into a stay, or blank
        k8[k] = key;
        const unsigned e32 = (unsigned)(key >> 32);
        pbest = pbest > e32 ? pbest : e32;
      }
      // 16-lane shuffle max -> parentBest (no same-address atomics)
      #pragma unroll
      for (int m = 1; m <= 8; m <<= 1) {
        const unsigned o = (unsigned)__shfl_xor((int)pbest, m, 64);
        pbest = pbest > o ? pbest : o;
      }
      if ((tid & 15) == 0) thsub[32 + i] = pbest;
    }
    if (tid < BEAM) {
      const int j = tid;
      if (mergeCnt[j] > 1) anom = 1;
      float pnbm;
      if (mergeCnt[j] == 1) {
        const int mf = mergeFrom[j];
        const int mi = mf >> 8, mc = mf & 255;
        const float e = (mc == 0) ? NEGF
            : (((mc == blast[cb][mi]) ? bpb[cb][mi] : sptot[mi]) + lpc[mc]);
        const float a = s_pnb[j];
        const float m = fmaxf(a, e);
        const float s = expf(a - m) + expf(e - m);  // stay term first (ref order)
        pnbm = m + logf(s);
      } else {
        pnbm = s_pnb[j];
      }
      s_pnbm[j] = pnbm;
      thsub[j] = encf(lae(s_pb[j], pnbm));
    }
    if (tid == 511) scnt[par ^ 1] = 0;   // reset next step's survivor counter
    __syncthreads();  // B

    const bool an = (anom != 0);
    bool dorare = an;
    if (!an) {
      // ======== phase F: wave-redundant u32 bitonic theta + filter +
      //          wave-scan compaction (1 atomic per wave) ========
      const int ln = tid & 63;
      const unsigned sorted = bitonic64_u32_desc(ln, thsub[ln]);
      const unsigned thr = (unsigned)__shfl((int)sorted, 31, 64);  // 32nd largest

      int myn = 0;
      #pragma unroll
      for (int k = 0; k < 8; ++k) myn += ((unsigned)(k8[k] >> 32) >= thr) ? 1 : 0;
      const bool stayS = (tid < BEAM) && (thsub[tid] >= thr);
      myn += stayS ? 1 : 0;
      int pfx = myn;
      #pragma unroll
      for (int d = 1; d < 64; d <<= 1) {
        const int o = __shfl_up(pfx, d, 64);
        if (ln >= d) pfx += o;
      }
      const int wtot = __shfl(pfx, 63, 64);
      int wbase = 0;
      if (ln == 0 && wtot) wbase = atomicAdd(&scnt[par], wtot);
      wbase = __shfl(wbase, 0, 64);
      if (wbase + wtot > SCAP) {
        if (ln == 0 && wtot) ovf = 1;
      } else if (myn) {
        int o = wbase + pfx - myn;
        #pragma unroll
        for (int k = 0; k < 8; ++k) {
          if ((unsigned)(k8[k] >> 32) >= thr) {
            skey[o] = k8[k];
            sidx[o] = (unsigned)(BEAM + i * NCLS + (c0 + k));
            ++o;
          }
        }
        if (stayS) {
          skey[o] = ((unsigned long long)thsub[tid] << 32) |
                    (unsigned long long)lowkey((unsigned)bhash[cb][tid]);
          sidx[o] = (unsigned)tid;
        }
      }
      __syncthreads();  // D
      dorare = (ovf != 0);
    }

    if (!dorare) {
      // ======== phase R: rank-by-count + update; idle threads do housekeeping ==
      const int scr = scnt[par];
      if (tid < scr) {                           // scr <= 256: rankers are tid<256
        const unsigned long long kq = skey[tid];
        int rank = 0;
        for (int p0 = 0; p0 < scr; p0 += 16) {
          #pragma unroll
          for (int pp = 0; pp < 16; ++pp) {
            const unsigned long long kp = skey[p0 + pp];   // padded, in-bounds
            rank += ((p0 + pp) < scr && kp > kq) ? 1 : 0;
          }
        }
        if (rank < BEAM) {
          const int j = rank;
          const unsigned s = sidx[tid];
          int nh, p, cls, ex; float npb, npnb;
          if (s < BEAM) {                     // stay-rooted segment
            p = (int)s; cls = 0; ex = 0;
            nh = bhash[cb][p];
            npb = s_pb[p];
            npnb = s_pnbm[p];
          } else {                            // standalone extend
            const unsigned q = s - BEAM;
            p = (int)(q >> 7); cls = (int)(q & 127); ex = 1;
            nh = (int)((unsigned)bhash[cb][p] * HPRIME + (unsigned)(cls + 1));
            npb = NEGF;
            npnb = (cls == 0) ? NEGF
                 : (((cls == blast[cb][p]) ? bpb[cb][p] : sptot[p]) + lpc[cls]);
          }
          const int plen = blen[cb][p], plast = blast[cb][p];
          const int nb = cb ^ 1;
          bhash[nb][j] = nh; bpb[nb][j] = npb; bpnb[nb][j] = npnb;
          blen[nb][j]  = plen + ex;
          blast[nb][j] = ex ? cls : plast;
          bp[t * BEAM + j] = (unsigned short)(p | (cls << 5) | (ex << 12));
        }
      }
      if (tid >= 256) {                          // housekeeping for next step
        unsigned* mtw = (unsigned*)mergeTo;
        const int base = tid - 256;
        #pragma unroll
        for (int m = 0; m < 4; ++m) mtw[base + m * 256] = 0xFFFFFFFFu;
        if (haspre) lpbuf[par ^ 1][tid - 256] = pre;
      }
      if (tid >= 64 && tid < 64 + BEAM) mergeCnt[tid - 64] = 0;
      __syncthreads();  // E
    } else {
      // ================= RARE PATH: full hash table (proven R1 semantics) =====
      for (int m = tid; m < TBL; m += 512) {
        tkey[m] = EMPTYK; tmax[m] = 0u; tsum[m] = 0u; tmin[m] = 0xFFFFFFFFu;
      }
      __syncthreads();

      int eslot[8]; float ex_[8];
      {
        const float pbi = bpb[cb][i];
        const float pti = sptot[i];
        const int   lsti = blast[cb][i];
        const unsigned hb = (unsigned)bhash[cb][i] * HPRIME;
        #pragma unroll
        for (int k = 0; k < 8; ++k) {
          const int c = c0 + k;
          int h = (int)(hb + (unsigned)(c + 1));
          if (h == EMPTYK) h = (int)0x80000001u;
          const float x = (c == 0) ? NEGF : (((c == lsti) ? pbi : pti) + lpc[c]);
          const int s = tbl_insert(tkey, h);
          atomicMax(&tmax[s], encf(x));
          atomicMin(&tmin[s], (unsigned)(BEAM + i * NCLS + c));
          eslot[k] = s; ex_[k] = x;
        }
      }
      if (tid < BEAM) {
        const int s = tbl_insert(tkey, bhash[cb][tid]);
        atomicMax(&tmax[s], encf(s_pnb[tid]));
        atomicMin(&tmin[s], (unsigned)tid);
        stay_slot[tid] = s;
      }
      __syncthreads();

      #pragma unroll
      for (int k = 0; k < 8; ++k) {
        const int s = eslot[k];
        atomicAdd((float*)&tsum[s], expf(ex_[k] - decf(tmax[s])));
      }
      if (tid < BEAM) {
        const int s = stay_slot[tid];
        atomicAdd((float*)&tsum[s], expf(s_pnb[tid] - decf(tmax[s])));
      }
      __syncthreads();

      for (int m = tid; m < TBL; m += 512) {
        if (tkey[m] != EMPTYK) {
          const float mm = decf(tmax[m]);
          const float ss = __uint_as_float(tsum[m]);
          const float pnbm = mm + logf(ss);
          tmax[m] = __float_as_uint(pnbm);
          tsum[m] = encf(lae(NEGF, pnbm));
        }
      }
      __syncthreads();
      if (tid < BEAM) {
        const int s = stay_slot[tid];
        tsum[s] = encf(lae(s_pb[tid], __uint_as_float(tmax[s])));
      }
      __syncthreads();

      {
        const int wv = tid >> 6, ln = tid & 63;
        const int base = wv * (TBL / 8) + ln * (TBL / 512);
        unsigned long long kk2[TBL / 512];
        #pragma unroll
        for (int m = 0; m < TBL / 512; ++m) {
          const int idx = base + m;
          if (tkey[idx] != EMPTYK) {
            kk2[m] = ((unsigned long long)tsum[idx] << 32) |
                     (unsigned long long)lowkey((unsigned)tkey[idx]);
          } else kk2[m] = 0ull;
        }
        unsigned cons = 0;
        for (int it = 0; it < BEAM; ++it) {
          unsigned long long best = 0ull; int bi = -1;
          #pragma unroll
          for (int m = 0; m < TBL / 512; ++m)
            if (!((cons >> m) & 1u) && kk2[m] > best) { best = kk2[m]; bi = m; }
          unsigned long long wm = best;
          #pragma unroll
          for (int off = 32; off > 0; off >>= 1) {
            const unsigned long long o = shflx64(wm, off);
            if (o > wm) wm = o;
          }
          const unsigned long long ball = __ballot(best == wm && wm != 0ull);
          const int winner = ball ? (__ffsll((long long)ball) - 1) : -1;
          if (ln == winner) {
            cons |= 1u << bi;
            wkey[wv * BEAM + it] = wm;
            widx[wv * BEAM + it] = (unsigned)(base + bi);
          } else if (winner < 0 && ln == 0) {
            wkey[wv * BEAM + it] = 0ull;
            widx[wv * BEAM + it] = 0xFFFFFFFFu;
          }
        }
      }
      __syncthreads();
      if (tid < 64) {
        unsigned long long kk2[4]; unsigned ii[4];
        #pragma unroll
        for (int m = 0; m < 4; ++m) { kk2[m] = wkey[tid * 4 + m]; ii[m] = widx[tid * 4 + m]; }
        unsigned cons = 0;
        for (int it = 0; it < BEAM; ++it) {
          unsigned long long best = 0ull; int bi = -1;
          #pragma unroll
          for (int m = 0; m < 4; ++m)
            if (!((cons >> m) & 1u) && kk2[m] > best) { best = kk2[m]; bi = m; }
          unsigned long long wm = best;
          #pragma unroll
          for (int off = 32; off > 0; off >>= 1) {
            const unsigned long long o = shflx64(wm, off);
            if (o > wm) wm = o;
          }
          const unsigned long long ball = __ballot(best == wm && wm != 0ull);
          const int winner = ball ? (__ffsll((long long)ball) - 1) : -1;
          if (tid == winner) { cons |= 1u << bi; sel[it] = ii[bi]; }
          else if (winner < 0 && tid == 0) sel[it] = 0xFFFFFFFFu;
        }
      }
      __syncthreads();

      if (tid < BEAM) {
        const int j = tid;
        const unsigned s = sel[j];
        int nh, p, cls, ex; float npb, npnb;
        if (s != 0xFFFFFFFFu) {
          nh = tkey[s];
          npnb = __uint_as_float(tmax[s]);
          npb = NEGF;
          #pragma unroll
          for (int q = 0; q < BEAM; ++q)
            if (stay_slot[q] == (int)s) npb = s_pb[q];
          const unsigned mi = tmin[s];
          ex  = (mi >= BEAM) ? 1 : 0;
          p   = ex ? (int)((mi - BEAM) >> 7) : (int)mi;
          cls = ex ? (int)((mi - BEAM) & 127) : 0;
          p &= 31;
        } else {
          nh = 0x7F000000 + j; npb = NEGF; npnb = NEGF; p = j; cls = 0; ex = 0;
        }
        const int plen = blen[cb][p], plast = blast[cb][p];
        const int nb = cb ^ 1;
        bhash[nb][j] = nh; bpb[nb][j] = npb; bpnb[nb][j] = npnb;
        blen[nb][j]  = plen + ex;
        blast[nb][j] = ex ? cls : plast;
        bp[t * BEAM + j] = (unsigned short)(p | (cls << 5) | (ex << 12));
      }
      // per-step resets (fast path does these in phase R)
      {
        unsigned* mtw = (unsigned*)mergeTo;
        for (int m = tid; m < (BEAM * NCLS) / 4; m += 512) mtw[m] = 0xFFFFFFFFu;
      }
      if (tid >= 64 && tid < 64 + BEAM) mergeCnt[tid - 64] = 0;
      if (tid == 511) { anom = 0; ovf = 0; }
      if (haspre) lpbuf[par ^ 1][tid - 256] = pre;
      __syncthreads();
    }
    cb ^= 1;
  }

  // ---- final top-1 + path reconstruction via backpointers
  if (tid == 0) {
    float bt = -3.4e38f; int bj = 0;
    for (int j = 0; j < BEAM; ++j) {
      const float tt = lae(bpb[cb][j], bpnb[cb][j]);
      if (tt > bt) { bt = tt; bj = j; }   // strict > : lowest index wins ties
    }
    int cur = bj;
    int pos = blen[cb][bj];
    flen_s = pos;
    for (int tt = L - 1; tt >= 0; --tt) {
      const unsigned short e = bp[tt * BEAM + cur];
      const int p = e & 31, cl = (e >> 5) & 127, ex = (e >> 12) & 1;
      if (ex) { --pos; if (pos >= 0) seqbuf[pos] = cl; }
      cur = p;
    }
  }
  __syncthreads();
  const int fl = flen_s;
  for (int k = tid; k < T_MAX; k += 512) {
    out[(size_t)b * T_MAX + k] = (k < fl) ? seqbuf[k] : 0;
  }
}

extern "C" void kernel_launch(void* const* d_in, const int* in_sizes, int n_in,
                              void* d_out, int out_size, void* d_ws, size_t ws_size,
                              hipStream_t stream) {
  const float* data = (const float*)d_in[0];   // [512, 64, 128] f32 log-probs
  const int*   dlen = (const int*)d_in[1];     // [64] int32
  int* out = (int*)d_out;                      // [64, 512] int32
  (void)in_sizes; (void)n_in; (void)out_size; (void)d_ws; (void)ws_size;
  hipLaunchKernelGGL(ctc_beam_kernel, dim3(BATCH), dim3(512), 0, stream,
                     data, dlen, out);
}

// Round 14
// 2200.412 us; speedup vs baseline: 1.6698x; 1.0276x over previous
//
#include <hip/hip_runtime.h>
#include <stdint.h>

#define T_MAX 512
#define BATCH 64
#define NCLS  128
#define BEAM  32
#define TBL   6144
#define NEGF  (-1e30f)
#define EMPTYK ((int)0x80000000)
#define HPRIME 1000003u
#define SCAP  256
#define NTHR  1024

// jnp.logaddexp: max + log1p(exp(-|a-b|)) (all values finite here)
__device__ __forceinline__ float lae(float a, float b) {
  float mx = fmaxf(a, b);
  return mx + log1pf(expf(-fabsf(a - b)));
}
// monotonic float <-> uint mapping for ordering / atomicMax on floats
__device__ __forceinline__ unsigned encf(float x) {
  unsigned v = __float_as_uint(x);
  return (v & 0x80000000u) ? ~v : (v | 0x80000000u);
}
__device__ __forceinline__ float decf(unsigned u) {
  unsigned v = (u & 0x80000000u) ? (u ^ 0x80000000u) : ~u;
  return __uint_as_float(v);
}
__device__ __forceinline__ unsigned lowkey(unsigned h) {
  return 0xFFFFFFFFu - (h ^ 0x80000000u);   // smaller signed hash ranks higher
}

__device__ __forceinline__ int tbl_insert(int* key, int h) {
  unsigned x = (unsigned)h * 2654435761u;
  x ^= x >> 16;
  int j = (int)(((unsigned long long)x * (unsigned long long)TBL) >> 32);
  for (;;) {
    int cur = key[j];
    if (cur == EMPTYK) cur = atomicCAS(&key[j], EMPTYK, h);
    if (cur == EMPTYK || cur == h) return j;
    ++j; if (j == TBL) j = 0;
  }
}

__device__ __forceinline__ unsigned long long shflx64(unsigned long long v, int m) {
  unsigned lo = (unsigned)__shfl_xor((int)(unsigned)v, m, 64);
  unsigned hi = (unsigned)__shfl_xor((int)(unsigned)(v >> 32), m, 64);
  return ((unsigned long long)hi << 32) | lo;
}

// Descending bitonic sort of 64 x u32 across one wave (R3-verified network, R=1)
__device__ __forceinline__ unsigned bitonic64_u32_desc(int ln, unsigned v) {
  #pragma unroll
  for (int size = 2; size <= 64; size <<= 1) {
    #pragma unroll
    for (int stride = size >> 1; stride > 0; stride >>= 1) {
      const unsigned o = (unsigned)__shfl_xor((int)v, stride, 64);
      const bool keepMax = (((ln & size) == 0) == ((ln & stride) == 0));
      v = keepMax ? (v > o ? v : o) : (v < o ? v : o);
    }
  }
  return v;
}

__global__ __launch_bounds__(NTHR, 1)
void ctc_beam_kernel(const float* __restrict__ data,
                     const int* __restrict__ dlen,
                     int* __restrict__ out) {
  // rare-path hash table — touched only on anomalies / overflow
  __shared__ int       tkey[TBL];
  __shared__ unsigned  tmax[TBL];
  __shared__ unsigned  tsum[TBL];
  __shared__ unsigned  tmin[TBL];
  __shared__ unsigned short bp[T_MAX * BEAM];  // backptr: parent|cls<<5|ext<<12
  __shared__ __align__(16) float lpbuf[2][NCLS];
  __shared__ int   bhash[2][BEAM];
  __shared__ float bpb[2][BEAM], bpnb[2][BEAM];
  __shared__ int   blen[2][BEAM], blast[2][BEAM];
  __shared__ float sptot[BEAM], s_pb[BEAM], s_pnb[BEAM], s_pnbm[BEAM];
  __shared__ int   stay_slot[BEAM];
  __shared__ unsigned char mergeTo[BEAM * NCLS];  // 0xFF = not merged
  __shared__ int mergeCnt[BEAM], mergeFrom[BEAM];
  __shared__ unsigned thsub[64];          // [0..31]=stay keys, [32..63]=parentBest
  __shared__ int anom, ovf;
  __shared__ int scnt[2];                 // parity-buffered survivor count
  __shared__ unsigned long long skey[SCAP + 16];  // +16 pad for batched reads
  __shared__ unsigned sidx[SCAP];
  // rare-path selection scratch
  __shared__ unsigned long long wkey[16 * BEAM];
  __shared__ unsigned widx[16 * BEAM];
  __shared__ unsigned sel[BEAM];
  __shared__ int seqbuf[T_MAX];
  __shared__ int flen_s;

  const int tid = threadIdx.x;   // 0..1023, 16 waves
  const int b = blockIdx.x;
  int L = dlen[b];
  L = L < 0 ? 0 : (L > T_MAX ? T_MAX : L);

  if (tid < BEAM) {
    bhash[0][tid] = tid;
    bpb[0][tid]   = (tid == 0) ? 0.0f : NEGF;
    bpnb[0][tid]  = NEGF;
    blen[0][tid]  = 0;
    blast[0][tid] = -1;
    mergeCnt[tid] = 0;
  }
  {
    unsigned* mtw = (unsigned*)mergeTo;
    for (int m = tid; m < (BEAM * NCLS) / 4; m += NTHR) mtw[m] = 0xFFFFFFFFu;
  }
  if (tid == 0) { anom = 0; ovf = 0; scnt[0] = 0; scnt[1] = 0; }
  if (tid < NCLS && L > 0) lpbuf[0][tid] = data[(size_t)b * NCLS + tid];
  __syncthreads();

  int cb = 0;
  for (int t = 0; t < L; ++t) {
    const int par = t & 1;
    const bool haspre = (tid >= 512) && (tid < 512 + NCLS) && (t + 1 < L);
    float pre = 0.0f;
    if (haspre) pre = data[((size_t)(t + 1) * BATCH + b) * NCLS + (tid - 512)];
    float* lpc = lpbuf[par];

    // ======== phase D: stays + exact merge detection ========
    if (tid < BEAM) {
      const float pbv = bpb[cb][tid], pnbv = bpnb[cb][tid];
      const float pt = lae(pbv, pnbv);
      sptot[tid] = pt;
      s_pb[tid]  = pt + lpc[0];
      const int lsti = blast[cb][tid];
      s_pnb[tid] = pnbv + ((lsti >= 0) ? lpc[lsti] : NEGF);
    }
    {  // exactly one (j, i2) pair per thread
      const int j = tid >> 5, i2 = tid & 31;
      const unsigned hj = (unsigned)bhash[cb][j];
      const unsigned hip = (unsigned)bhash[cb][i2] * HPRIME;
      const unsigned c = hj - hip - 1u;
      if (c < (unsigned)NCLS) {                 // extend(i2,c) merges stay j
        atomicAdd(&mergeCnt[j], 1);
        mergeFrom[j] = (i2 << 8) | (int)c;
        mergeTo[i2 * NCLS + (int)c] = (unsigned char)j;
      }
      if (j < i2) {                              // extend-extend collision?
        const unsigned d = (hj - (unsigned)bhash[cb][i2]) * HPRIME;
        if (d + 127u <= 254u) anom = 1;
      }
    }
    __syncthreads();  // A

    // ======== phase K: extend keys (4 classes/thread) + parent best + stays ==
    const int i  = tid >> 5;
    const int c0 = (tid & 31) << 2;
    unsigned long long k4[4];
    {
      const float pbi = bpb[cb][i];
      const float pti = sptot[i];
      const int   lsti = blast[cb][i];
      const unsigned hb = (unsigned)bhash[cb][i] * HPRIME;
      const float4 l0 = ((const float4*)(lpc + c0))[0];
      const float lv[4] = {l0.x, l0.y, l0.z, l0.w};
      const unsigned m0 = ((const unsigned*)&mergeTo[i * NCLS + c0])[0];
      unsigned pbest = 0u;
      #pragma unroll
      for (int k = 0; k < 4; ++k) {
        const int c = c0 + k;
        const unsigned mb = (m0 >> (8 * k)) & 0xFFu;
        const float x = (c == 0) ? NEGF : (((c == lsti) ? pbi : pti) + lv[k]);
        const float tot = fmaxf(x, NEGF);   // == lae(NEGF,x) bitwise
        const unsigned h = hb + (unsigned)(c + 1);
        unsigned long long key =
            ((unsigned long long)encf(tot) << 32) |
            (unsigned long long)lowkey(h);
        if (mb != 0xFFu || c == 0) key = 0ull;   // merged into a stay, or blank
        k4[k] = key;
        const unsigned e32 = (unsigned)(key >> 32);
        pbest = pbest > e32 ? pbest : e32;
      }
      // 32-lane (half-wave) shuffle max -> parentBest (no same-address atomics)
      #pragma unroll
      for (int m = 1; m <= 16; m <<= 1) {
        const unsigned o = (unsigned)__shfl_xor((int)pbest, m, 64);
        pbest = pbest > o ? pbest : o;
      }
      if ((tid & 31) == 0) thsub[32 + i] = pbest;
    }
    if (tid < BEAM) {
      const int j = tid;
      if (mergeCnt[j] > 1) anom = 1;
      float pnbm;
      if (mergeCnt[j] == 1) {
        const int mf = mergeFrom[j];
        const int mi = mf >> 8, mc = mf & 255;
        const float e = (mc == 0) ? NEGF
            : (((mc == blast[cb][mi]) ? bpb[cb][mi] : sptot[mi]) + lpc[mc]);
        const float a = s_pnb[j];
        const float m = fmaxf(a, e);
        const float s = expf(a - m) + expf(e - m);  // stay term first (ref order)
        pnbm = m + logf(s);
      } else {
        pnbm = s_pnb[j];
      }
      s_pnbm[j] = pnbm;
      thsub[j] = encf(lae(s_pb[j], pnbm));
    }
    if (tid == NTHR - 1) scnt[par ^ 1] = 0;   // reset next step's counter
    __syncthreads();  // B

    const bool an = (anom != 0);
    bool dorare = an;
    if (!an) {
      // ======== phase F: wave-redundant u32 bitonic theta + filter +
      //          wave-scan compaction (1 atomic per wave) ========
      const int ln = tid & 63;
      const unsigned sorted = bitonic64_u32_desc(ln, thsub[ln]);
      const unsigned thr = (unsigned)__shfl((int)sorted, 31, 64);  // 32nd largest

      int myn = 0;
      #pragma unroll
      for (int k = 0; k < 4; ++k) myn += ((unsigned)(k4[k] >> 32) >= thr) ? 1 : 0;
      const bool stayS = (tid < BEAM) && (thsub[tid] >= thr);
      myn += stayS ? 1 : 0;
      int pfx = myn;
      #pragma unroll
      for (int d = 1; d < 64; d <<= 1) {
        const int o = __shfl_up(pfx, d, 64);
        if (ln >= d) pfx += o;
      }
      const int wtot = __shfl(pfx, 63, 64);
      int wbase = 0;
      if (ln == 0 && wtot) wbase = atomicAdd(&scnt[par], wtot);
      wbase = __shfl(wbase, 0, 64);
      if (wbase + wtot > SCAP) {
        if (ln == 0 && wtot) ovf = 1;
      } else if (myn) {
        int o = wbase + pfx - myn;
        #pragma unroll
        for (int k = 0; k < 4; ++k) {
          if ((unsigned)(k4[k] >> 32) >= thr) {
            skey[o] = k4[k];
            sidx[o] = (unsigned)(BEAM + i * NCLS + (c0 + k));
            ++o;
          }
        }
        if (stayS) {
          skey[o] = ((unsigned long long)thsub[tid] << 32) |
                    (unsigned long long)lowkey((unsigned)bhash[cb][tid]);
          sidx[o] = (unsigned)tid;
        }
      }
      __syncthreads();  // D
      dorare = (ovf != 0);
    }

    if (!dorare) {
      // ======== phase R: rank-by-count + update; idle threads do housekeeping ==
      const int scr = scnt[par];
      if (tid < scr) {                           // scr <= 256: rankers are tid<256
        const unsigned long long kq = skey[tid];
        int rank = 0;
        for (int p0 = 0; p0 < scr; p0 += 16) {
          #pragma unroll
          for (int pp = 0; pp < 16; ++pp) {
            const unsigned long long kp = skey[p0 + pp];   // padded, in-bounds
            rank += ((p0 + pp) < scr && kp > kq) ? 1 : 0;
          }
        }
        if (rank < BEAM) {
          const int j = rank;
          const unsigned s = sidx[tid];
          int nh, p, cls, ex; float npb, npnb;
          if (s < BEAM) {                     // stay-rooted segment
            p = (int)s; cls = 0; ex = 0;
            nh = bhash[cb][p];
            npb = s_pb[p];
            npnb = s_pnbm[p];
          } else {                            // standalone extend
            const unsigned q = s - BEAM;
            p = (int)(q >> 7); cls = (int)(q & 127); ex = 1;
            nh = (int)((unsigned)bhash[cb][p] * HPRIME + (unsigned)(cls + 1));
            npb = NEGF;
            npnb = (cls == 0) ? NEGF
                 : (((cls == blast[cb][p]) ? bpb[cb][p] : sptot[p]) + lpc[cls]);
          }
          const int plen = blen[cb][p], plast = blast[cb][p];
          const int nb = cb ^ 1;
          bhash[nb][j] = nh; bpb[nb][j] = npb; bpnb[nb][j] = npnb;
          blen[nb][j]  = plen + ex;
          blast[nb][j] = ex ? cls : plast;
          bp[t * BEAM + j] = (unsigned short)(p | (cls << 5) | (ex << 12));
        }
      }
      if (tid >= 512) {                          // housekeeping for next step
        unsigned* mtw = (unsigned*)mergeTo;
        const int base = tid - 512;
        #pragma unroll
        for (int m = 0; m < 2; ++m) mtw[base + m * 512] = 0xFFFFFFFFu;
        if (haspre) lpbuf[par ^ 1][tid - 512] = pre;
      }
      if (tid >= 64 && tid < 64 + BEAM) mergeCnt[tid - 64] = 0;
      __syncthreads();  // E
    } else {
      // ================= RARE PATH: full hash table (proven R1 semantics) =====
      for (int m = tid; m < TBL; m += NTHR) {
        tkey[m] = EMPTYK; tmax[m] = 0u; tsum[m] = 0u; tmin[m] = 0xFFFFFFFFu;
      }
      __syncthreads();

      int eslot[4]; float ex_[4];
      {
        const float pbi = bpb[cb][i];
        const float pti = sptot[i];
        const int   lsti = blast[cb][i];
        const unsigned hb = (unsigned)bhash[cb][i] * HPRIME;
        #pragma unroll
        for (int k = 0; k < 4; ++k) {
          const int c = c0 + k;
          int h = (int)(hb + (unsigned)(c + 1));
          if (h == EMPTYK) h = (int)0x80000001u;
          const float x = (c == 0) ? NEGF : (((c == lsti) ? pbi : pti) + lpc[c]);
          const int s = tbl_insert(tkey, h);
          atomicMax(&tmax[s], encf(x));
          atomicMin(&tmin[s], (unsigned)(BEAM + i * NCLS + c));
          eslot[k] = s; ex_[k] = x;
        }
      }
      if (tid < BEAM) {
        const int s = tbl_insert(tkey, bhash[cb][tid]);
        atomicMax(&tmax[s], encf(s_pnb[tid]));
        atomicMin(&tmin[s], (unsigned)tid);
        stay_slot[tid] = s;
      }
      __syncthreads();

      #pragma unroll
      for (int k = 0; k < 4; ++k) {
        const int s = eslot[k];
        atomicAdd((float*)&tsum[s], expf(ex_[k] - decf(tmax[s])));
      }
      if (tid < BEAM) {
        const int s = stay_slot[tid];
        atomicAdd((float*)&tsum[s], expf(s_pnb[tid] - decf(tmax[s])));
      }
      __syncthreads();

      for (int m = tid; m < TBL; m += NTHR) {
        if (tkey[m] != EMPTYK) {
          const float mm = decf(tmax[m]);
          const float ss = __uint_as_float(tsum[m]);
          const float pnbm = mm + logf(ss);
          tmax[m] = __float_as_uint(pnbm);
          tsum[m] = encf(lae(NEGF, pnbm));
        }
      }
      __syncthreads();
      if (tid < BEAM) {
        const int s = stay_slot[tid];
        tsum[s] = encf(lae(s_pb[tid], __uint_as_float(tmax[s])));
      }
      __syncthreads();

      {
        const int wv = tid >> 6, ln = tid & 63;
        const int base = wv * (TBL / 16) + ln * (TBL / NTHR);
        unsigned long long kk2[TBL / NTHR];
        #pragma unroll
        for (int m = 0; m < TBL / NTHR; ++m) {
          const int idx = base + m;
          if (tkey[idx] != EMPTYK) {
            kk2[m] = ((unsigned long long)tsum[idx] << 32) |
                     (unsigned long long)lowkey((unsigned)tkey[idx]);
          } else kk2[m] = 0ull;
        }
        unsigned cons = 0;
        for (int it = 0; it < BEAM; ++it) {
          unsigned long long best = 0ull; int bi = -1;
          #pragma unroll
          for (int m = 0; m < TBL / NTHR; ++m)
            if (!((cons >> m) & 1u) && kk2[m] > best) { best = kk2[m]; bi = m; }
          unsigned long long wm = best;
          #pragma unroll
          for (int off = 32; off > 0; off >>= 1) {
            const unsigned long long o = shflx64(wm, off);
            if (o > wm) wm = o;
          }
          const unsigned long long ball = __ballot(best == wm && wm != 0ull);
          const int winner = ball ? (__ffsll((long long)ball) - 1) : -1;
          if (ln == winner) {
            cons |= 1u << bi;
            wkey[wv * BEAM + it] = wm;
            widx[wv * BEAM + it] = (unsigned)(base + bi);
          } else if (winner < 0 && ln == 0) {
            wkey[wv * BEAM + it] = 0ull;
            widx[wv * BEAM + it] = 0xFFFFFFFFu;
          }
        }
      }
      __syncthreads();
      if (tid < 64) {  // merge 16 sorted lists (8 consecutive entries per lane)
        unsigned long long mk[8]; unsigned mx[8];
        #pragma unroll
        for (int m = 0; m < 8; ++m) { mk[m] = wkey[tid * 8 + m]; mx[m] = widx[tid * 8 + m]; }
        unsigned cons = 0;
        for (int it = 0; it < BEAM; ++it) {
          unsigned long long best = 0ull; int bi = -1;
          #pragma unroll
          for (int m = 0; m < 8; ++m)
            if (!((cons >> m) & 1u) && mk[m] > best) { best = mk[m]; bi = m; }
          unsigned long long wm = best;
          #pragma unroll
          for (int off = 32; off > 0; off >>= 1) {
            const unsigned long long o = shflx64(wm, off);
            if (o > wm) wm = o;
          }
          const unsigned long long ball = __ballot(best == wm && wm != 0ull);
          const int winner = ball ? (__ffsll((long long)ball) - 1) : -1;
          if (tid == winner) { cons |= 1u << bi; sel[it] = mx[bi]; }
          else if (winner < 0 && tid == 0) sel[it] = 0xFFFFFFFFu;
        }
      }
      __syncthreads();

      if (tid < BEAM) {
        const int j = tid;
        const unsigned s = sel[j];
        int nh, p, cls, ex; float npb, npnb;
        if (s != 0xFFFFFFFFu) {
          nh = tkey[s];
          npnb = __uint_as_float(tmax[s]);
          npb = NEGF;
          #pragma unroll
          for (int q = 0; q < BEAM; ++q)
            if (stay_slot[q] == (int)s) npb = s_pb[q];
          const unsigned mi = tmin[s];
          ex  = (mi >= BEAM) ? 1 : 0;
          p   = ex ? (int)((mi - BEAM) >> 7) : (int)mi;
          cls = ex ? (int)((mi - BEAM) & 127) : 0;
          p &= 31;
        } else {
          nh = 0x7F000000 + j; npb = NEGF; npnb = NEGF; p = j; cls = 0; ex = 0;
        }
        const int plen = blen[cb][p], plast = blast[cb][p];
        const int nb = cb ^ 1;
        bhash[nb][j] = nh; bpb[nb][j] = npb; bpnb[nb][j] = npnb;
        blen[nb][j]  = plen + ex;
        blast[nb][j] = ex ? cls : plast;
        bp[t * BEAM + j] = (unsigned short)(p | (cls << 5) | (ex << 12));
      }
      // per-step resets (fast path does these in phase R)
      {
        unsigned* mtw = (unsigned*)mergeTo;
        for (int m = tid; m < (BEAM * NCLS) / 4; m += NTHR) mtw[m] = 0xFFFFFFFFu;
      }
      if (tid >= 64 && tid < 64 + BEAM) mergeCnt[tid - 64] = 0;
      if (tid == NTHR - 1) { anom = 0; ovf = 0; }
      if (haspre) lpbuf[par ^ 1][tid - 512] = pre;
      __syncthreads();
    }
    cb ^= 1;
  }

  // ---- final top-1 + path reconstruction via backpointers
  if (tid == 0) {
    float bt = -3.4e38f; int bj = 0;
    for (int j = 0; j < BEAM; ++j) {
      const float tt = lae(bpb[cb][j], bpnb[cb][j]);
      if (tt > bt) { bt = tt; bj = j; }   // strict > : lowest index wins ties
    }
    int cur = bj;
    int pos = blen[cb][bj];
    flen_s = pos;
    for (int tt = L - 1; tt >= 0; --tt) {
      const unsigned short e = bp[tt * BEAM + cur];
      const int p = e & 31, cl = (e >> 5) & 127, ex = (e >> 12) & 1;
      if (ex) { --pos; if (pos >= 0) seqbuf[pos] = cl; }
      cur = p;
    }
  }
  __syncthreads();
  const int fl = flen_s;
  for (int k = tid; k < T_MAX; k += NTHR) {
    out[(size_t)b * T_MAX + k] = (k < fl) ? seqbuf[k] : 0;
  }
}

extern "C" void kernel_launch(void* const* d_in, const int* in_sizes, int n_in,
                              void* d_out, int out_size, void* d_ws, size_t ws_size,
                              hipStream_t stream) {
  const float* data = (const float*)d_in[0];   // [512, 64, 128] f32 log-probs
  const int*   dlen = (const int*)d_in[1];     // [64] int32
  int* out = (int*)d_out;                      // [64, 512] int32
  (void)in_sizes; (void)n_in; (void)out_size; (void)d_ws; (void)ws_size;
  hipLaunchKernelGGL(ctc_beam_kernel, dim3(BATCH), dim3(NTHR), 0, stream,
                     data, dlen, out);
}